// Round 9
// baseline (275.210 us; speedup 1.0000x reference)
//
#include <hip/hip_runtime.h>
#include <hip/hip_fp16.h>

// GCN 2-layer: N=50000 nodes, E=800000 edges, 128 -> 128(relu) -> 64
// CSR-by-dst via binned counting sort -> h' = dinv*(x@W) via split-bf16 MFMA
// -> flat fp16 [N][C] -> XCD-pinned channel-sliced gather aggregate at
// CONSTANT 8B/lane (R8 insight: slice 32ch = 64B/row = 8 lanes; 8 edge
// subgroups/wave keeps gathers/edge + lines/gather + VALU invariant while
// making each 3.2MB slice XCD-L2-resident) -> fold shfl_xor(8,16,32) ->
// dinv*sum + bias (+relu), float4 stores.
// R4 failed slicing because it dropped to 4B/lane (3x instr cost); this keeps
// the instruction budget of the flat kernel exactly.

#define N_NODES 50000
#define N_EDGES 800000
#define BINW    128
#define NBIN    391                    // ceil(50000/128)
#define CAP     2560                   // mean 2046, ~11 sigma margin
#define B_CHUNK 4096
#define NB_SCAT ((N_EDGES + B_CHUNK - 1) / B_CHUNK)   // 196

typedef __bf16 bf16x8 __attribute__((ext_vector_type(8)));
typedef float  f32x4  __attribute__((ext_vector_type(4)));

// ---------------- CSR build: binned counting sort ----------------

__global__ __launch_bounds__(256) void bin_scatter_kernel(
        const int* __restrict__ src, const int* __restrict__ dst,
        int* __restrict__ gcur, unsigned* __restrict__ ebin) {
    __shared__ int cnt[512];          // per-bin counts (NBIN padded to 512)
    __shared__ int boff[512];         // bin start in staging
    __shared__ int bcur[512];
    __shared__ int gbase[512];
    __shared__ unsigned stage[B_CHUNK];
    __shared__ int ex[256];
    int tid = threadIdx.x;
    int e0 = blockIdx.x * B_CHUNK;

    cnt[tid] = 0; cnt[tid + 256] = 0;
    __syncthreads();

    unsigned key[16]; int bins[16];
#pragma unroll
    for (int i = 0; i < 16; i++) {
        int e = e0 + tid + i * 256;               // coalesced
        if (e < N_EDGES) {
            int d = dst[e], s = src[e];
            key[i]  = ((unsigned)d << 16) | (unsigned)s;
            bins[i] = d >> 7;
            atomicAdd(&cnt[bins[i]], 1);
        } else bins[i] = -1;
    }
    __syncthreads();

    // exclusive scan of 512 bin counts with 256 threads (2 bins each)
    int a = cnt[2 * tid], b = cnt[2 * tid + 1];
    ex[tid] = a + b;
    __syncthreads();
    for (int off = 1; off < 256; off <<= 1) {
        int t = (tid >= off) ? ex[tid - off] : 0;
        __syncthreads();
        ex[tid] += t;
        __syncthreads();
    }
    int myex = ex[tid] - (a + b);
    boff[2 * tid] = myex;     boff[2 * tid + 1] = myex + a;
    bcur[2 * tid] = myex;     bcur[2 * tid + 1] = myex + a;
    __syncthreads();

    // compact into bin-contiguous staging
#pragma unroll
    for (int i = 0; i < 16; i++) {
        if (bins[i] >= 0) {
            int p = atomicAdd(&bcur[bins[i]], 1);
            stage[p] = key[i];
        }
    }

    // bulk-reserve global bin space (one atomic per non-empty (block,bin))
    __syncthreads();
    for (int b2 = tid; b2 < NBIN; b2 += 256) {
        int c = cnt[b2];
        gbase[b2] = (c > 0) ? atomicAdd(&gcur[b2], c) : 0;
    }
    __syncthreads();

    // write out: element i of staging -> ebin[bin*CAP + gbase[bin] + (i - boff[bin])]
    int total = N_EDGES - e0; if (total > B_CHUNK) total = B_CHUNK;
    for (int i = tid; i < total; i += 256) {
        unsigned k = stage[i];
        int bin = (int)(k >> 23);                 // dst>>7
        int idx = gbase[bin] + (i - boff[bin]);
        if (idx < CAP) ebin[(size_t)bin * CAP + idx] = k;  // guard (11-sigma)
    }
}

__global__ __launch_bounds__(256) void bin_count_kernel(
        const unsigned* __restrict__ ebin, const int* __restrict__ gcur,
        int* __restrict__ deg) {
    __shared__ int dl[BINW];
    int bin = blockIdx.x, tid = threadIdx.x;
    if (tid < BINW) dl[tid] = 0;
    __syncthreads();
    int cnt = gcur[bin]; if (cnt > CAP) cnt = CAP;
    const unsigned* eb = ebin + (size_t)bin * CAP;
    for (int i = tid; i < cnt; i += 256)
        atomicAdd(&dl[(eb[i] >> 16) & 127], 1);
    __syncthreads();
    int node = bin * BINW + tid;
    if (tid < BINW && node < N_NODES) deg[node] = dl[tid];
}

__global__ __launch_bounds__(256) void bin_fill_kernel(
        const unsigned* __restrict__ ebin, const int* __restrict__ gcur,
        const int* __restrict__ row_off, int* __restrict__ ssrc) {
    __shared__ int cur[BINW];
    int bin = blockIdx.x, tid = threadIdx.x;
    int node = bin * BINW + tid;
    if (tid < BINW) cur[tid] = (node < N_NODES) ? row_off[node] : 0;
    __syncthreads();
    int cnt = gcur[bin]; if (cnt > CAP) cnt = CAP;
    const unsigned* eb = ebin + (size_t)bin * CAP;
    for (int i = tid; i < cnt; i += 256) {
        unsigned k = eb[i];
        int p = atomicAdd(&cur[(k >> 16) & 127], 1);
        ssrc[p] = (int)(k & 0xFFFFu);
    }
}

// ---------------- scans ----------------

__global__ void scan_part_kernel(const int* __restrict__ deg, int* __restrict__ partials) {
    __shared__ int red[256];
    int tid = threadIdx.x;
    int base = blockIdx.x * 1024 + tid * 4;
    int s = 0;
#pragma unroll
    for (int i = 0; i < 4; i++) { int idx = base + i; if (idx < N_NODES) s += deg[idx]; }
    red[tid] = s; __syncthreads();
    for (int off = 128; off > 0; off >>= 1) {
        if (tid < off) red[tid] += red[tid + off];
        __syncthreads();
    }
    if (tid == 0) partials[blockIdx.x] = red[0];
}

__global__ void scan_blocks_kernel(int* partials, int nb) {
    int tid = threadIdx.x;            // 64 threads, one wave
    int orig = (tid < nb) ? partials[tid] : 0;
    int v = orig;
    for (int off = 1; off < 64; off <<= 1) {
        int t = __shfl_up(v, off, 64);
        if (tid >= off) v += t;
    }
    if (tid < nb) partials[tid] = v - orig;   // exclusive
}

__global__ void scan_final_kernel(const int* __restrict__ deg, const int* __restrict__ poff,
                                  int* __restrict__ row_off, float* __restrict__ dinv) {
    __shared__ int sc[256];
    int tid = threadIdx.x;
    int base = blockIdx.x * 1024 + tid * 4;
    int v[4]; int s = 0;
#pragma unroll
    for (int i = 0; i < 4; i++) { int idx = base + i; v[i] = (idx < N_NODES) ? deg[idx] : 0; s += v[i]; }
    sc[tid] = s; __syncthreads();
    for (int off = 1; off < 256; off <<= 1) {
        int t = (tid >= off) ? sc[tid - off] : 0;
        __syncthreads();
        sc[tid] += t;
        __syncthreads();
    }
    int run = sc[tid] - s + poff[blockIdx.x];
#pragma unroll
    for (int i = 0; i < 4; i++) {
        int idx = base + i;
        if (idx < N_NODES) {
            row_off[idx] = run;
            dinv[idx]    = rsqrtf((float)(v[i] + 1));   // +1 self-loop
            run += v[i];
        }
    }
}

// ---------------- W prep: f32 [K=128][N] -> hi/lo bf16 B-fragments ----------------
template<int N>
__global__ void wprep_kernel(const float* __restrict__ W,
                             __bf16* __restrict__ hi, __bf16* __restrict__ lo) {
    int idx = blockIdx.x * 256 + threadIdx.x;     // total (N/16)*4*64
    if (idx >= (N / 16) * 4 * 64) return;
    int l = idx & 63;
    int s = (idx >> 6) & 3;
    int c = idx >> 8;
    int n = c * 16 + (l & 15);
    int k0 = s * 32 + (l >> 4) * 8;
#pragma unroll
    for (int j = 0; j < 8; j++) {
        float w = W[(k0 + j) * N + n];
        __bf16 h = (__bf16)w;
        hi[idx * 8 + j] = h;
        lo[idx * 8 + j] = (__bf16)(w - (float)h);
    }
}

// ---------------- GEMM: hs[row][OUTC] = fp16( dinv[row] * (X @ W)[row] ) ----------
template<int OUTC>
__global__ __launch_bounds__(256) void gemm_mfma_kernel(
        const float* __restrict__ X, const __bf16* __restrict__ Whi,
        const __bf16* __restrict__ Wlo, const float* __restrict__ dinv,
        __half* __restrict__ hs) {
    constexpr int NC = OUTC / 16;
    int tid = threadIdx.x;
    int w = tid >> 6, lane = tid & 63;
    int q = lane >> 4, lr = lane & 15;
    int rb = blockIdx.x * 64 + w * 16;
    int row = rb + lr;
    int rowc = (row < N_NODES) ? row : (N_NODES - 1);

    f32x4 acc[NC];
#pragma unroll
    for (int c = 0; c < NC; c++) acc[c] = (f32x4){0.f, 0.f, 0.f, 0.f};

#pragma unroll
    for (int s = 0; s < 4; s++) {
        const float* xp = X + (size_t)rowc * 128 + s * 32 + q * 8;
        float4 x0 = *(const float4*)xp;
        float4 x1 = *(const float4*)(xp + 4);
        float xv[8] = {x0.x, x0.y, x0.z, x0.w, x1.x, x1.y, x1.z, x1.w};
        bf16x8 a_hi, a_lo;
#pragma unroll
        for (int j = 0; j < 8; j++) {
            __bf16 h = (__bf16)xv[j];
            a_hi[j] = h;
            a_lo[j] = (__bf16)(xv[j] - (float)h);
        }
#pragma unroll
        for (int c = 0; c < NC; c++) {
            size_t fo = (size_t)((c * 4 + s) * 64 + lane) * 8;
            bf16x8 bh = *(const bf16x8*)(Whi + fo);
            bf16x8 bl = *(const bf16x8*)(Wlo + fo);
            acc[c] = __builtin_amdgcn_mfma_f32_16x16x32_bf16(a_hi, bh, acc[c], 0, 0, 0);
            acc[c] = __builtin_amdgcn_mfma_f32_16x16x32_bf16(a_lo, bh, acc[c], 0, 0, 0);
            acc[c] = __builtin_amdgcn_mfma_f32_16x16x32_bf16(a_hi, bl, acc[c], 0, 0, 0);
        }
    }

    // C/D layout: col = c*16 + lr, row(within 16) = q*4 + r
#pragma unroll
    for (int r = 0; r < 4; r++) {
        int grow = rb + q * 4 + r;
        if (grow < N_NODES) {
            float sc = dinv[grow];
#pragma unroll
            for (int c = 0; c < NC; c++) {
                hs[(size_t)grow * OUTC + c * 16 + lr] = __float2half(acc[c][r] * sc);
            }
        }
    }
}

// ---------------- Sliced aggregate (constant 8B/lane) ----------------
// hs: fp16 flat [N][CH]. Slice = 32 channels = 8 float2/row. Wave = 1 node:
// 8 edge-subgroups (sg) x 8 channel-lanes (cl). 16 edges/iter (matches mean
// degree 16), 2 gathers in flight, indices broadcast within subgroup.
// Region (blockIdx&7) pins slice s to XCDs {s*NPART .. } so each 3.2MB slice
// stays in one XCD's L2 (heuristic; correctness independent).
template<int CH, int NSLICE, bool RELU>
__global__ __launch_bounds__(256) void aggregate_sliced_kernel(
        const __half* __restrict__ hs, const int* __restrict__ row_off,
        const int* __restrict__ deg, const int* __restrict__ ssrc,
        const float* __restrict__ dinv, const float* __restrict__ bias,
        float* __restrict__ out) {
    constexpr int NPART = 8 / NSLICE;                 // node partitions
    constexpr int ROWQ  = CH / 4;                     // row length in float2
    constexpr int NPP   = N_NODES / NPART;            // 25000 / 12500 (exact)
    int region = blockIdx.x & 7;
    int slice  = region / NPART;
    int part   = region % NPART;
    int node = part * NPP + (blockIdx.x >> 3) * 4 + (threadIdx.x >> 6);
    int lane = threadIdx.x & 63;
    int sg = lane >> 3;       // edge subgroup 0..7
    int cl = lane & 7;        // channel lane 0..7 (4 ch each)

    const float2* Hq = (const float2*)hs;
    int rq = slice * 8 + cl;                          // float2 offset in row
    int beg = row_off[node];
    int d   = deg[node];
    float di = dinv[node];

    float4 acc = make_float4(0.f, 0.f, 0.f, 0.f);
    for (int j = 0; j < d; j += 16) {
        int i0 = j + sg, i1 = j + 8 + sg;
        int s0 = ssrc[beg + ((i0 < d) ? i0 : (d - 1))];
        int s1 = ssrc[beg + ((i1 < d) ? i1 : (d - 1))];
        float2 v0 = Hq[(size_t)s0 * ROWQ + rq];
        float2 v1 = Hq[(size_t)s1 * ROWQ + rq];
        if (i0 < d) {
            float2 f0 = __half22float2(((const __half2*)&v0)[0]);
            float2 f1 = __half22float2(((const __half2*)&v0)[1]);
            acc.x += f0.x; acc.y += f0.y; acc.z += f1.x; acc.w += f1.y;
        }
        if (i1 < d) {
            float2 f0 = __half22float2(((const __half2*)&v1)[0]);
            float2 f1 = __half22float2(((const __half2*)&v1)[1]);
            acc.x += f0.x; acc.y += f0.y; acc.z += f1.x; acc.w += f1.y;
        }
    }
    // fold the 8 subgroups
    acc.x += __shfl_xor(acc.x, 8, 64);  acc.y += __shfl_xor(acc.y, 8, 64);
    acc.z += __shfl_xor(acc.z, 8, 64);  acc.w += __shfl_xor(acc.w, 8, 64);
    acc.x += __shfl_xor(acc.x, 16, 64); acc.y += __shfl_xor(acc.y, 16, 64);
    acc.z += __shfl_xor(acc.z, 16, 64); acc.w += __shfl_xor(acc.w, 16, 64);
    acc.x += __shfl_xor(acc.x, 32, 64); acc.y += __shfl_xor(acc.y, 32, 64);
    acc.z += __shfl_xor(acc.z, 32, 64); acc.w += __shfl_xor(acc.w, 32, 64);

    if (sg == 0) {
        float2 sv = Hq[(size_t)node * ROWQ + rq];     // self-loop term
        float2 f0 = __half22float2(((const __half2*)&sv)[0]);
        float2 f1 = __half22float2(((const __half2*)&sv)[1]);
        float4 b = ((const float4*)bias)[slice * 8 + cl];
        float4 o;
        o.x = fmaf(di, acc.x + f0.x, b.x);
        o.y = fmaf(di, acc.y + f0.y, b.y);
        o.z = fmaf(di, acc.z + f1.x, b.z);
        o.w = fmaf(di, acc.w + f1.y, b.w);
        if (RELU) {
            o.x = fmaxf(o.x, 0.f); o.y = fmaxf(o.y, 0.f);
            o.z = fmaxf(o.z, 0.f); o.w = fmaxf(o.w, 0.f);
        }
        ((float4*)out)[(size_t)node * (CH / 4) + slice * 8 + cl] = o;
    }
}

// ---------------- launch ----------------

extern "C" void kernel_launch(void* const* d_in, const int* in_sizes, int n_in,
                              void* d_out, int out_size, void* d_ws, size_t ws_size,
                              hipStream_t stream) {
    const float* x  = (const float*)d_in[0];   // [N,128]
    const int*   ei = (const int*)d_in[1];     // [2,E]
    const float* W1 = (const float*)d_in[2];   // [128,128]
    const float* b1 = (const float*)d_in[3];   // [128]
    const float* W2 = (const float*)d_in[4];   // [128,64]
    const float* b2 = (const float*)d_in[5];   // [64]
    float* out = (float*)d_out;                // [N,64]

    const int* src = ei;
    const int* dst = ei + N_EDGES;

    char* p = (char*)d_ws;
    size_t off = 0;
    auto alloc = [&](size_t bytes) { void* q = p + off; off += (bytes + 255) & ~(size_t)255; return q; };
    float*    dinv    = (float*)   alloc(N_NODES * 4);
    int*      deg     = (int*)     alloc(N_NODES * 4);
    int*      row_off = (int*)     alloc(N_NODES * 4);
    int*      gcur    = (int*)     alloc(NBIN * 4);
    int*      parts   = (int*)     alloc(64 * 4);
    int*      ssrc    = (int*)     alloc(N_EDGES * 4);
    unsigned* ebin    = (unsigned*)alloc((size_t)NBIN * CAP * 4);   // 4.0 MB
    __bf16*   w1hi    = (__bf16*)  alloc(128 * 128 * 2);
    __bf16*   w1lo    = (__bf16*)  alloc(128 * 128 * 2);
    __bf16*   w2hi    = (__bf16*)  alloc(128 * 64 * 2);
    __bf16*   w2lo    = (__bf16*)  alloc(128 * 64 * 2);
    __half*   hs1     = (__half*)  alloc((size_t)N_NODES * 128 * 2);
    __half*   hs2     = (__half*)  alloc((size_t)N_NODES * 64 * 2);
    float*    x2      = (float*)   alloc((size_t)N_NODES * 128 * 4);

    const int nb_scan = (N_NODES + 1023) / 1024;       // 49

    hipMemsetAsync(gcur, 0, NBIN * sizeof(int), stream);
    bin_scatter_kernel<<<NB_SCAT, 256, 0, stream>>>(src, dst, gcur, ebin);
    bin_count_kernel<<<NBIN, 256, 0, stream>>>(ebin, gcur, deg);
    scan_part_kernel<<<nb_scan, 256, 0, stream>>>(deg, parts);
    scan_blocks_kernel<<<1, 64, 0, stream>>>(parts, nb_scan);
    scan_final_kernel<<<nb_scan, 256, 0, stream>>>(deg, parts, row_off, dinv);
    bin_fill_kernel<<<NBIN, 256, 0, stream>>>(ebin, gcur, row_off, ssrc);

    wprep_kernel<128><<<8, 256, 0, stream>>>(W1, w1hi, w1lo);
    wprep_kernel<64> <<<4, 256, 0, stream>>>(W2, w2hi, w2lo);

    // layer 1: hs1 = fp16(dinv*(x@W1)); x2 = relu(dinv*(self+sum) + b1)
    gemm_mfma_kernel<128><<<(N_NODES + 63) / 64, 256, 0, stream>>>(x, w1hi, w1lo, dinv, hs1);
    // grid: 4 slices x 2 parts x (25000/4) blocks = 50000
    aggregate_sliced_kernel<128, 4, true><<<8 * (N_NODES / 2 / 4), 256, 0, stream>>>(
        hs1, row_off, deg, ssrc, dinv, b1, x2);

    // layer 2: hs2 = fp16(dinv*(x2@W2)); out = dinv*(self+sum) + b2
    gemm_mfma_kernel<64><<<(N_NODES + 63) / 64, 256, 0, stream>>>(x2, w2hi, w2lo, dinv, hs2);
    // grid: 2 slices x 4 parts x (12500/4) blocks = 25000
    aggregate_sliced_kernel<64, 2, false><<<8 * (N_NODES / 4 / 4), 256, 0, stream>>>(
        hs2, row_off, deg, ssrc, dinv, b2, out);
}

// Round 10
// 193.772 us; speedup vs baseline: 1.4203x; 1.4203x over previous
//
#include <hip/hip_runtime.h>
#include <hip/hip_fp16.h>

// GCN 2-layer: N=50000 nodes, E=800000 edges, 128 -> 128(relu) -> 64
// R10: flat fp16 aggregate (R8 - proven best) + pipeline collapsed 13->7
// launches: per-bin CSR (row_off = bin*CAP + local prefix) removes the
// global scan entirely; bin_build = histogram+scan+fill in one kernel;
// prep = both W-preps + gcur zeroing.
// Evidence log: R4/R9 killed sliced layouts (4B/lane instr cost; 64B rows on
// 128B lines thrash 4MB L2 -> FETCH 103MB). Flat gather = 86.6MB compulsory.

#define N_NODES 50000
#define N_EDGES 800000
#define BINW    128
#define NBIN    391                    // ceil(50000/128)
#define CAP     2560                   // mean bin load 2046, ~11 sigma margin
#define B_CHUNK 4096
#define NB_SCAT ((N_EDGES + B_CHUNK - 1) / B_CHUNK)   // 196

typedef __bf16 bf16x8 __attribute__((ext_vector_type(8)));
typedef float  f32x4  __attribute__((ext_vector_type(4)));

// ---------------- prep: W1/W2 -> hi/lo bf16 B-fragments, zero gcur ----------------
// B-frag layout (mfma_f32_16x16x32_bf16): lane l holds B[k0+(l>>4)*8+j][n0+(l&15)].
template<int N>
__device__ inline void wprep_body(const float* __restrict__ W,
                                  __bf16* __restrict__ hi, __bf16* __restrict__ lo,
                                  int idx) {
    if (idx >= (N / 16) * 4 * 64) return;
    int l = idx & 63;
    int s = (idx >> 6) & 3;
    int c = idx >> 8;
    int n = c * 16 + (l & 15);
    int k0 = s * 32 + (l >> 4) * 8;
#pragma unroll
    for (int j = 0; j < 8; j++) {
        float w = W[(k0 + j) * N + n];
        __bf16 h = (__bf16)w;
        hi[idx * 8 + j] = h;
        lo[idx * 8 + j] = (__bf16)(w - (float)h);
    }
}

__global__ __launch_bounds__(256) void prep_kernel(
        const float* __restrict__ W1, const float* __restrict__ W2,
        __bf16* __restrict__ w1hi, __bf16* __restrict__ w1lo,
        __bf16* __restrict__ w2hi, __bf16* __restrict__ w2lo,
        int* __restrict__ gcur) {
    int b = blockIdx.x, tid = threadIdx.x;
    if (b < 8)       wprep_body<128>(W1, w1hi, w1lo, b * 256 + tid);
    else if (b < 12) wprep_body<64> (W2, w2hi, w2lo, (b - 8) * 256 + tid);
    else             for (int i = tid; i < NBIN; i += 256) gcur[i] = 0;
}

// ---------------- bin_scatter: one edge pass -> per-bin packed (dst<<16|src) -------

__global__ __launch_bounds__(256) void bin_scatter_kernel(
        const int* __restrict__ src, const int* __restrict__ dst,
        int* __restrict__ gcur, unsigned* __restrict__ ebin) {
    __shared__ int cnt[512];
    __shared__ int boff[512];
    __shared__ int bcur[512];
    __shared__ int gbase[512];
    __shared__ unsigned stage[B_CHUNK];
    __shared__ int ex[256];
    int tid = threadIdx.x;
    int e0 = blockIdx.x * B_CHUNK;

    cnt[tid] = 0; cnt[tid + 256] = 0;
    __syncthreads();

    unsigned key[16]; int bins[16];
#pragma unroll
    for (int i = 0; i < 16; i++) {
        int e = e0 + tid + i * 256;               // coalesced
        if (e < N_EDGES) {
            int d = dst[e], s = src[e];
            key[i]  = ((unsigned)d << 16) | (unsigned)s;
            bins[i] = d >> 7;
            atomicAdd(&cnt[bins[i]], 1);
        } else bins[i] = -1;
    }
    __syncthreads();

    // exclusive scan of 512 bin counts with 256 threads (2 bins each)
    int a = cnt[2 * tid], b = cnt[2 * tid + 1];
    ex[tid] = a + b;
    __syncthreads();
    for (int off = 1; off < 256; off <<= 1) {
        int t = (tid >= off) ? ex[tid - off] : 0;
        __syncthreads();
        ex[tid] += t;
        __syncthreads();
    }
    int myex = ex[tid] - (a + b);
    boff[2 * tid] = myex;     boff[2 * tid + 1] = myex + a;
    bcur[2 * tid] = myex;     bcur[2 * tid + 1] = myex + a;
    __syncthreads();

    // compact into bin-contiguous staging
#pragma unroll
    for (int i = 0; i < 16; i++) {
        if (bins[i] >= 0) {
            int p = atomicAdd(&bcur[bins[i]], 1);
            stage[p] = key[i];
        }
    }

    // bulk-reserve global bin space (one atomic per non-empty (block,bin))
    __syncthreads();
    for (int b2 = tid; b2 < NBIN; b2 += 256) {
        int c = cnt[b2];
        gbase[b2] = (c > 0) ? atomicAdd(&gcur[b2], c) : 0;
    }
    __syncthreads();

    int total = N_EDGES - e0; if (total > B_CHUNK) total = B_CHUNK;
    for (int i = tid; i < total; i += 256) {
        unsigned k = stage[i];
        int bin = (int)(k >> 23);                 // dst>>7
        int idx = gbase[bin] + (i - boff[bin]);
        if (idx < CAP) ebin[(size_t)bin * CAP + idx] = k;  // guard (11-sigma)
    }
}

// ---------------- bin_build: histogram + local scan + fill, one kernel -------------
// row_off[node] = bin*CAP + local_prefix  (per-bin CSR: no global scan needed).
__global__ __launch_bounds__(256) void bin_build_kernel(
        const unsigned* __restrict__ ebin, const int* __restrict__ gcur,
        int* __restrict__ deg, int* __restrict__ row_off,
        float* __restrict__ dinv, int* __restrict__ ssrc) {
    __shared__ int dl[BINW];
    __shared__ int pref[BINW];
    __shared__ int cur[BINW];
    int bin = blockIdx.x, tid = threadIdx.x;
    if (tid < BINW) dl[tid] = 0;
    __syncthreads();
    int cnt = gcur[bin]; if (cnt > CAP) cnt = CAP;
    const unsigned* eb = ebin + (size_t)bin * CAP;
    for (int i = tid; i < cnt; i += 256)
        atomicAdd(&dl[(eb[i] >> 16) & 127], 1);
    __syncthreads();
    // Hillis-Steele inclusive scan over 128 counts
    if (tid < BINW) pref[tid] = dl[tid];
    __syncthreads();
    for (int off = 1; off < BINW; off <<= 1) {
        int t = 0;
        if (tid < BINW && tid >= off) t = pref[tid - off];
        __syncthreads();
        if (tid < BINW) pref[tid] += t;
        __syncthreads();
    }
    if (tid < BINW) {
        int ex = pref[tid] - dl[tid];             // exclusive prefix
        cur[tid] = ex;
        int node = bin * BINW + tid;
        if (node < N_NODES) {
            deg[node]     = dl[tid];
            row_off[node] = bin * CAP + ex;
            dinv[node]    = rsqrtf((float)(dl[tid] + 1));   // +1 self-loop
        }
    }
    __syncthreads();
    for (int i = tid; i < cnt; i += 256) {
        unsigned k = eb[i];
        int p = atomicAdd(&cur[(k >> 16) & 127], 1);
        ssrc[(size_t)bin * CAP + p] = (int)(k & 0xFFFFu);
    }
}

// ---------------- GEMM: hs[row][OUTC] = fp16( dinv[row] * (X @ W)[row] ) ----------
template<int OUTC>
__global__ __launch_bounds__(256) void gemm_mfma_kernel(
        const float* __restrict__ X, const __bf16* __restrict__ Whi,
        const __bf16* __restrict__ Wlo, const float* __restrict__ dinv,
        __half* __restrict__ hs) {
    constexpr int NC = OUTC / 16;
    int tid = threadIdx.x;
    int w = tid >> 6, lane = tid & 63;
    int q = lane >> 4, lr = lane & 15;
    int rb = blockIdx.x * 64 + w * 16;
    int row = rb + lr;
    int rowc = (row < N_NODES) ? row : (N_NODES - 1);

    f32x4 acc[NC];
#pragma unroll
    for (int c = 0; c < NC; c++) acc[c] = (f32x4){0.f, 0.f, 0.f, 0.f};

#pragma unroll
    for (int s = 0; s < 4; s++) {
        const float* xp = X + (size_t)rowc * 128 + s * 32 + q * 8;
        float4 x0 = *(const float4*)xp;
        float4 x1 = *(const float4*)(xp + 4);
        float xv[8] = {x0.x, x0.y, x0.z, x0.w, x1.x, x1.y, x1.z, x1.w};
        bf16x8 a_hi, a_lo;
#pragma unroll
        for (int j = 0; j < 8; j++) {
            __bf16 h = (__bf16)xv[j];
            a_hi[j] = h;
            a_lo[j] = (__bf16)(xv[j] - (float)h);
        }
#pragma unroll
        for (int c = 0; c < NC; c++) {
            size_t fo = (size_t)((c * 4 + s) * 64 + lane) * 8;
            bf16x8 bh = *(const bf16x8*)(Whi + fo);
            bf16x8 bl = *(const bf16x8*)(Wlo + fo);
            acc[c] = __builtin_amdgcn_mfma_f32_16x16x32_bf16(a_hi, bh, acc[c], 0, 0, 0);
            acc[c] = __builtin_amdgcn_mfma_f32_16x16x32_bf16(a_lo, bh, acc[c], 0, 0, 0);
            acc[c] = __builtin_amdgcn_mfma_f32_16x16x32_bf16(a_hi, bl, acc[c], 0, 0, 0);
        }
    }

    // C/D layout: col = c*16 + lr, row(within 16) = q*4 + r
#pragma unroll
    for (int r = 0; r < 4; r++) {
        int grow = rb + q * 4 + r;
        if (grow < N_NODES) {
            float sc = dinv[grow];
#pragma unroll
            for (int c = 0; c < NC; c++) {
                hs[(size_t)grow * OUTC + c * 16 + lr] = __float2half(acc[c][r] * sc);
            }
        }
    }
}

// ---------------- Aggregate CH=128: wave/node, 8B/lane = 2 rows/instr -------------
template<bool RELU>
__global__ __launch_bounds__(256) void aggregate128_kernel(
        const __half* __restrict__ hs, const int* __restrict__ row_off,
        const int* __restrict__ deg, const int* __restrict__ ssrc,
        const float* __restrict__ dinv, const float* __restrict__ bias,
        float* __restrict__ out) {
    int node = (blockIdx.x * 256 + threadIdx.x) >> 6;
    int lane = threadIdx.x & 63;
    if (node >= N_NODES) return;
    int beg = row_off[node];
    int d   = deg[node];
    float di = dinv[node];
    int hf = lane >> 5, sl = lane & 31;
    const float2* Hq = (const float2*)hs;        // [N][32] 8B chunks
    float4 acc = make_float4(0.f, 0.f, 0.f, 0.f);
    for (int j = 0; j < d; j += 16) {
        int s[8]; float2 v[8];
#pragma unroll
        for (int u = 0; u < 8; u++) {
            int i = j + 2 * u + hf;
            s[u] = ssrc[beg + ((i < d) ? i : (d - 1))];
        }
#pragma unroll
        for (int u = 0; u < 8; u++) v[u] = Hq[(size_t)s[u] * 32 + sl];
#pragma unroll
        for (int u = 0; u < 8; u++) {
            if (j + 2 * u + hf < d) {
                float2 f0 = __half22float2(((const __half2*)&v[u])[0]);
                float2 f1 = __half22float2(((const __half2*)&v[u])[1]);
                acc.x += f0.x; acc.y += f0.y; acc.z += f1.x; acc.w += f1.y;
            }
        }
    }
    acc.x += __shfl_xor(acc.x, 32, 64);
    acc.y += __shfl_xor(acc.y, 32, 64);
    acc.z += __shfl_xor(acc.z, 32, 64);
    acc.w += __shfl_xor(acc.w, 32, 64);
    if (hf == 0) {
        float2 sv = Hq[(size_t)node * 32 + sl];  // self-loop
        float2 f0 = __half22float2(((const __half2*)&sv)[0]);
        float2 f1 = __half22float2(((const __half2*)&sv)[1]);
        float4 b = ((const float4*)bias)[sl];
        float4 o;
        o.x = fmaf(di, acc.x + f0.x, b.x);
        o.y = fmaf(di, acc.y + f0.y, b.y);
        o.z = fmaf(di, acc.z + f1.x, b.z);
        o.w = fmaf(di, acc.w + f1.y, b.w);
        if (RELU) {
            o.x = fmaxf(o.x, 0.f); o.y = fmaxf(o.y, 0.f);
            o.z = fmaxf(o.z, 0.f); o.w = fmaxf(o.w, 0.f);
        }
        ((float4*)out)[(size_t)node * 32 + sl] = o;
    }
}

// ---------------- Aggregate CH=64: wave/node, 8B/lane = 4 rows/instr --------------
// 16 edges/iter (4 gathers) matches mean degree 16 — R8's 32-edge batch wasted
// half its gathers on clamped duplicates for typical nodes.
__global__ __launch_bounds__(256) void aggregate64_kernel(
        const __half* __restrict__ hs, const int* __restrict__ row_off,
        const int* __restrict__ deg, const int* __restrict__ ssrc,
        const float* __restrict__ dinv, const float* __restrict__ bias,
        float* __restrict__ out) {
    int node = (blockIdx.x * 256 + threadIdx.x) >> 6;
    int lane = threadIdx.x & 63;
    if (node >= N_NODES) return;
    int beg = row_off[node];
    int d   = deg[node];
    float di = dinv[node];
    int qt = lane >> 4, sl = lane & 15;
    const float2* Hq = (const float2*)hs;        // [N][16] 8B chunks
    float4 acc = make_float4(0.f, 0.f, 0.f, 0.f);
    for (int j = 0; j < d; j += 16) {
        int s[4]; float2 v[4];
#pragma unroll
        for (int u = 0; u < 4; u++) {
            int i = j + 4 * u + qt;
            s[u] = ssrc[beg + ((i < d) ? i : (d - 1))];
        }
#pragma unroll
        for (int u = 0; u < 4; u++) v[u] = Hq[(size_t)s[u] * 16 + sl];
#pragma unroll
        for (int u = 0; u < 4; u++) {
            if (j + 4 * u + qt < d) {
                float2 f0 = __half22float2(((const __half2*)&v[u])[0]);
                float2 f1 = __half22float2(((const __half2*)&v[u])[1]);
                acc.x += f0.x; acc.y += f0.y; acc.z += f1.x; acc.w += f1.y;
            }
        }
    }
    acc.x += __shfl_xor(acc.x, 16, 64);
    acc.y += __shfl_xor(acc.y, 16, 64);
    acc.z += __shfl_xor(acc.z, 16, 64);
    acc.w += __shfl_xor(acc.w, 16, 64);
    acc.x += __shfl_xor(acc.x, 32, 64);
    acc.y += __shfl_xor(acc.y, 32, 64);
    acc.z += __shfl_xor(acc.z, 32, 64);
    acc.w += __shfl_xor(acc.w, 32, 64);
    if (lane < 16) {
        float2 sv = Hq[(size_t)node * 16 + sl];  // self-loop
        float2 f0 = __half22float2(((const __half2*)&sv)[0]);
        float2 f1 = __half22float2(((const __half2*)&sv)[1]);
        float4 b = ((const float4*)bias)[sl];
        float4 o;
        o.x = fmaf(di, acc.x + f0.x, b.x);
        o.y = fmaf(di, acc.y + f0.y, b.y);
        o.z = fmaf(di, acc.z + f1.x, b.z);
        o.w = fmaf(di, acc.w + f1.y, b.w);
        ((float4*)out)[(size_t)node * 16 + sl] = o;
    }
}

// ---------------- launch ----------------

extern "C" void kernel_launch(void* const* d_in, const int* in_sizes, int n_in,
                              void* d_out, int out_size, void* d_ws, size_t ws_size,
                              hipStream_t stream) {
    const float* x  = (const float*)d_in[0];   // [N,128]
    const int*   ei = (const int*)d_in[1];     // [2,E]
    const float* W1 = (const float*)d_in[2];   // [128,128]
    const float* b1 = (const float*)d_in[3];   // [128]
    const float* W2 = (const float*)d_in[4];   // [128,64]
    const float* b2 = (const float*)d_in[5];   // [64]
    float* out = (float*)d_out;                // [N,64]

    const int* src = ei;
    const int* dst = ei + N_EDGES;

    char* p = (char*)d_ws;
    size_t off = 0;
    auto alloc = [&](size_t bytes) { void* q = p + off; off += (bytes + 255) & ~(size_t)255; return q; };
    float*    dinv    = (float*)   alloc(N_NODES * 4);
    int*      deg     = (int*)     alloc(N_NODES * 4);
    int*      row_off = (int*)     alloc(N_NODES * 4);
    int*      gcur    = (int*)     alloc(NBIN * 4);
    int*      ssrc    = (int*)     alloc((size_t)NBIN * CAP * 4);   // 4.0 MB
    unsigned* ebin    = (unsigned*)alloc((size_t)NBIN * CAP * 4);   // 4.0 MB
    __bf16*   w1hi    = (__bf16*)  alloc(128 * 128 * 2);
    __bf16*   w1lo    = (__bf16*)  alloc(128 * 128 * 2);
    __bf16*   w2hi    = (__bf16*)  alloc(128 * 64 * 2);
    __bf16*   w2lo    = (__bf16*)  alloc(128 * 64 * 2);
    __half*   hs1     = (__half*)  alloc((size_t)N_NODES * 128 * 2);
    __half*   hs2     = (__half*)  alloc((size_t)N_NODES * 64 * 2);
    float*    x2      = (float*)   alloc((size_t)N_NODES * 128 * 4);

    // 7 launches total
    prep_kernel<<<13, 256, 0, stream>>>(W1, W2, w1hi, w1lo, w2hi, w2lo, gcur);
    bin_scatter_kernel<<<NB_SCAT, 256, 0, stream>>>(src, dst, gcur, ebin);
    bin_build_kernel<<<NBIN, 256, 0, stream>>>(ebin, gcur, deg, row_off, dinv, ssrc);

    gemm_mfma_kernel<128><<<(N_NODES + 63) / 64, 256, 0, stream>>>(x, w1hi, w1lo, dinv, hs1);
    aggregate128_kernel<true><<<(N_NODES * 64 + 255) / 256, 256, 0, stream>>>(
        hs1, row_off, deg, ssrc, dinv, b1, x2);

    gemm_mfma_kernel<64><<<(N_NODES + 63) / 64, 256, 0, stream>>>(x2, w2hi, w2lo, dinv, hs2);
    aggregate64_kernel<<<(N_NODES * 64 + 255) / 256, 256, 0, stream>>>(
        hs2, row_off, deg, ssrc, dinv, b2, out);
}

// Round 11
// 184.939 us; speedup vs baseline: 1.4881x; 1.0478x over previous
//
#include <hip/hip_runtime.h>
#include <hip/hip_fp16.h>

// GCN 2-layer: N=50000 nodes, E=800000 edges, 128 -> 128(relu) -> 64
// R11: sentinel-padded per-bin CSR. Each node's edge list padded to x32 with
// index N_NODES -> an all-zero hs row. Aggregate inner loop = pure
// load/cvt/add (no clamp, no predication); sentinel gathers hit one hot L1
// line and add exact zeros. agg64 restored to 8 gathers in flight.
// Evidence log: R2 in-flight depth = big win; R4/R9 sliced layouts dead;
// flat gather 86.6MB compulsory; R10 top-5 = harness poison fills only.

#define N_NODES 50000
#define N_EDGES 800000
#define BINW    128
#define NBIN    391                    // ceil(50000/128)
#define CAP     2560                   // mean bin load 2046, ~11 sigma margin
#define CAP2    6656                   // padded: 2560 + 128*31 = 6528 max
#define B_CHUNK 4096
#define NB_SCAT ((N_EDGES + B_CHUNK - 1) / B_CHUNK)   // 196

typedef __bf16 bf16x8 __attribute__((ext_vector_type(8)));
typedef float  f32x4  __attribute__((ext_vector_type(4)));

// ---------------- prep: W-frags, zero gcur, zero sentinel rows ----------------
template<int N>
__device__ inline void wprep_body(const float* __restrict__ W,
                                  __bf16* __restrict__ hi, __bf16* __restrict__ lo,
                                  int idx) {
    if (idx >= (N / 16) * 4 * 64) return;
    int l = idx & 63;
    int s = (idx >> 6) & 3;
    int c = idx >> 8;
    int n = c * 16 + (l & 15);
    int k0 = s * 32 + (l >> 4) * 8;
#pragma unroll
    for (int j = 0; j < 8; j++) {
        float w = W[(k0 + j) * N + n];
        __bf16 h = (__bf16)w;
        hi[idx * 8 + j] = h;
        lo[idx * 8 + j] = (__bf16)(w - (float)h);
    }
}

__global__ __launch_bounds__(256) void prep_kernel(
        const float* __restrict__ W1, const float* __restrict__ W2,
        __bf16* __restrict__ w1hi, __bf16* __restrict__ w1lo,
        __bf16* __restrict__ w2hi, __bf16* __restrict__ w2lo,
        int* __restrict__ gcur, __half* __restrict__ hs1, __half* __restrict__ hs2) {
    int b = blockIdx.x, tid = threadIdx.x;
    if (b < 8)       wprep_body<128>(W1, w1hi, w1lo, b * 256 + tid);
    else if (b < 12) wprep_body<64> (W2, w2hi, w2lo, (b - 8) * 256 + tid);
    else {
        for (int i = tid; i < NBIN; i += 256) gcur[i] = 0;
        if (tid < 128) hs1[(size_t)N_NODES * 128 + tid] = __float2half(0.f);
        if (tid < 64)  hs2[(size_t)N_NODES * 64 + tid] = __float2half(0.f);
    }
}

// ---------------- bin_scatter: one edge pass -> per-bin packed (dst<<16|src) -------

__global__ __launch_bounds__(256) void bin_scatter_kernel(
        const int* __restrict__ src, const int* __restrict__ dst,
        int* __restrict__ gcur, unsigned* __restrict__ ebin) {
    __shared__ int cnt[512];
    __shared__ int boff[512];
    __shared__ int bcur[512];
    __shared__ int gbase[512];
    __shared__ unsigned stage[B_CHUNK];
    __shared__ int ex[256];
    int tid = threadIdx.x;
    int e0 = blockIdx.x * B_CHUNK;

    cnt[tid] = 0; cnt[tid + 256] = 0;
    __syncthreads();

    unsigned key[16]; int bins[16];
#pragma unroll
    for (int i = 0; i < 16; i++) {
        int e = e0 + tid + i * 256;               // coalesced
        if (e < N_EDGES) {
            int d = dst[e], s = src[e];
            key[i]  = ((unsigned)d << 16) | (unsigned)s;
            bins[i] = d >> 7;
            atomicAdd(&cnt[bins[i]], 1);
        } else bins[i] = -1;
    }
    __syncthreads();

    // exclusive scan of 512 bin counts with 256 threads (2 bins each)
    int a = cnt[2 * tid], b = cnt[2 * tid + 1];
    ex[tid] = a + b;
    __syncthreads();
    for (int off = 1; off < 256; off <<= 1) {
        int t = (tid >= off) ? ex[tid - off] : 0;
        __syncthreads();
        ex[tid] += t;
        __syncthreads();
    }
    int myex = ex[tid] - (a + b);
    boff[2 * tid] = myex;     boff[2 * tid + 1] = myex + a;
    bcur[2 * tid] = myex;     bcur[2 * tid + 1] = myex + a;
    __syncthreads();

    // compact into bin-contiguous staging
#pragma unroll
    for (int i = 0; i < 16; i++) {
        if (bins[i] >= 0) {
            int p = atomicAdd(&bcur[bins[i]], 1);
            stage[p] = key[i];
        }
    }

    // bulk-reserve global bin space (one atomic per non-empty (block,bin))
    __syncthreads();
    for (int b2 = tid; b2 < NBIN; b2 += 256) {
        int c = cnt[b2];
        gbase[b2] = (c > 0) ? atomicAdd(&gcur[b2], c) : 0;
    }
    __syncthreads();

    int total = N_EDGES - e0; if (total > B_CHUNK) total = B_CHUNK;
    for (int i = tid; i < total; i += 256) {
        unsigned k = stage[i];
        int bin = (int)(k >> 23);                 // dst>>7
        int idx = gbase[bin] + (i - boff[bin]);
        if (idx < CAP) ebin[(size_t)bin * CAP + idx] = k;  // guard (11-sigma)
    }
}

// ---------------- bin_build: histogram + padded scan + sentinel fill ---------------
// row_off[node] = bin*CAP2 + padded_prefix; lists padded to x32 with N_NODES.
__global__ __launch_bounds__(256) void bin_build_kernel(
        const unsigned* __restrict__ ebin, const int* __restrict__ gcur,
        int* __restrict__ deg, int* __restrict__ row_off,
        float* __restrict__ dinv, int* __restrict__ ssrc) {
    __shared__ int dl[BINW];
    __shared__ int pref[BINW];
    __shared__ int cur[BINW];
    __shared__ int padTotal;
    int bin = blockIdx.x, tid = threadIdx.x;
    if (tid < BINW) dl[tid] = 0;
    __syncthreads();
    int cnt = gcur[bin]; if (cnt > CAP) cnt = CAP;
    const unsigned* eb = ebin + (size_t)bin * CAP;
    for (int i = tid; i < cnt; i += 256)
        atomicAdd(&dl[(eb[i] >> 16) & 127], 1);
    __syncthreads();
    // Hillis-Steele inclusive scan over 128 PADDED counts
    int pc = 0;
    if (tid < BINW) { pc = (dl[tid] + 31) & ~31; pref[tid] = pc; }
    __syncthreads();
    for (int off = 1; off < BINW; off <<= 1) {
        int t = 0;
        if (tid < BINW && tid >= off) t = pref[tid - off];
        __syncthreads();
        if (tid < BINW) pref[tid] += t;
        __syncthreads();
    }
    if (tid < BINW) {
        int ex = pref[tid] - pc;                  // padded exclusive prefix
        cur[tid] = ex;
        int node = bin * BINW + tid;
        if (node < N_NODES) {
            deg[node]     = dl[tid];
            row_off[node] = bin * CAP2 + ex;
            dinv[node]    = rsqrtf((float)(dl[tid] + 1));   // +1 self-loop
        }
        if (tid == BINW - 1) padTotal = pref[tid];
    }
    __syncthreads();
    int pt = padTotal;
    int* sb = ssrc + (size_t)bin * CAP2;
    for (int i = tid; i < pt; i += 256) sb[i] = N_NODES;    // sentinel prefill
    __syncthreads();
    for (int i = tid; i < cnt; i += 256) {
        unsigned k = eb[i];
        int p = atomicAdd(&cur[(k >> 16) & 127], 1);
        sb[p] = (int)(k & 0xFFFFu);
    }
}

// ---------------- GEMM: hs[row][OUTC] = fp16( dinv[row] * (X @ W)[row] ) ----------
template<int OUTC>
__global__ __launch_bounds__(256) void gemm_mfma_kernel(
        const float* __restrict__ X, const __bf16* __restrict__ Whi,
        const __bf16* __restrict__ Wlo, const float* __restrict__ dinv,
        __half* __restrict__ hs) {
    constexpr int NC = OUTC / 16;
    int tid = threadIdx.x;
    int w = tid >> 6, lane = tid & 63;
    int q = lane >> 4, lr = lane & 15;
    int rb = blockIdx.x * 64 + w * 16;
    int row = rb + lr;
    int rowc = (row < N_NODES) ? row : (N_NODES - 1);

    f32x4 acc[NC];
#pragma unroll
    for (int c = 0; c < NC; c++) acc[c] = (f32x4){0.f, 0.f, 0.f, 0.f};

#pragma unroll
    for (int s = 0; s < 4; s++) {
        const float* xp = X + (size_t)rowc * 128 + s * 32 + q * 8;
        float4 x0 = *(const float4*)xp;
        float4 x1 = *(const float4*)(xp + 4);
        float xv[8] = {x0.x, x0.y, x0.z, x0.w, x1.x, x1.y, x1.z, x1.w};
        bf16x8 a_hi, a_lo;
#pragma unroll
        for (int j = 0; j < 8; j++) {
            __bf16 h = (__bf16)xv[j];
            a_hi[j] = h;
            a_lo[j] = (__bf16)(xv[j] - (float)h);
        }
#pragma unroll
        for (int c = 0; c < NC; c++) {
            size_t fo = (size_t)((c * 4 + s) * 64 + lane) * 8;
            bf16x8 bh = *(const bf16x8*)(Whi + fo);
            bf16x8 bl = *(const bf16x8*)(Wlo + fo);
            acc[c] = __builtin_amdgcn_mfma_f32_16x16x32_bf16(a_hi, bh, acc[c], 0, 0, 0);
            acc[c] = __builtin_amdgcn_mfma_f32_16x16x32_bf16(a_lo, bh, acc[c], 0, 0, 0);
            acc[c] = __builtin_amdgcn_mfma_f32_16x16x32_bf16(a_hi, bl, acc[c], 0, 0, 0);
        }
    }

    // C/D layout: col = c*16 + lr, row(within 16) = q*4 + r
#pragma unroll
    for (int r = 0; r < 4; r++) {
        int grow = rb + q * 4 + r;
        if (grow < N_NODES) {
            float sc = dinv[grow];
#pragma unroll
            for (int c = 0; c < NC; c++) {
                hs[(size_t)grow * OUTC + c * 16 + lr] = __float2half(acc[c][r] * sc);
            }
        }
    }
}

// ---------------- Aggregate CH=128: wave/node, 8B/lane = 2 rows/instr -------------
// Sentinel-padded lists: pure load/cvt/add, no clamp, no predication.
template<bool RELU>
__global__ __launch_bounds__(256) void aggregate128_kernel(
        const __half* __restrict__ hs, const int* __restrict__ row_off,
        const int* __restrict__ deg, const int* __restrict__ ssrc,
        const float* __restrict__ dinv, const float* __restrict__ bias,
        float* __restrict__ out) {
    int node = (blockIdx.x * 256 + threadIdx.x) >> 6;
    int lane = threadIdx.x & 63;
    if (node >= N_NODES) return;
    int beg = row_off[node];
    int d   = deg[node];
    float di = dinv[node];
    int hf = lane >> 5, sl = lane & 31;
    const float2* Hq = (const float2*)hs;        // [N+1][32] 8B chunks
    float4 acc = make_float4(0.f, 0.f, 0.f, 0.f);
    for (int j = 0; j < d; j += 16) {            // padded span covers ceil16(d)
        int s[8]; float2 v[8];
#pragma unroll
        for (int u = 0; u < 8; u++) s[u] = ssrc[beg + j + 2 * u + hf];
#pragma unroll
        for (int u = 0; u < 8; u++) v[u] = Hq[(size_t)s[u] * 32 + sl];
#pragma unroll
        for (int u = 0; u < 8; u++) {
            float2 f0 = __half22float2(((const __half2*)&v[u])[0]);
            float2 f1 = __half22float2(((const __half2*)&v[u])[1]);
            acc.x += f0.x; acc.y += f0.y; acc.z += f1.x; acc.w += f1.y;
        }
    }
    acc.x += __shfl_xor(acc.x, 32, 64);
    acc.y += __shfl_xor(acc.y, 32, 64);
    acc.z += __shfl_xor(acc.z, 32, 64);
    acc.w += __shfl_xor(acc.w, 32, 64);
    if (hf == 0) {
        float2 sv = Hq[(size_t)node * 32 + sl];  // self-loop
        float2 f0 = __half22float2(((const __half2*)&sv)[0]);
        float2 f1 = __half22float2(((const __half2*)&sv)[1]);
        float4 b = ((const float4*)bias)[sl];
        float4 o;
        o.x = fmaf(di, acc.x + f0.x, b.x);
        o.y = fmaf(di, acc.y + f0.y, b.y);
        o.z = fmaf(di, acc.z + f1.x, b.z);
        o.w = fmaf(di, acc.w + f1.y, b.w);
        if (RELU) {
            o.x = fmaxf(o.x, 0.f); o.y = fmaxf(o.y, 0.f);
            o.z = fmaxf(o.z, 0.f); o.w = fmaxf(o.w, 0.f);
        }
        ((float4*)out)[(size_t)node * 32 + sl] = o;
    }
}

// ---------------- Aggregate CH=64: wave/node, 8B/lane = 4 rows/instr --------------
// 32 edges/iter (matches pad granularity), 8 gathers in flight, no predication.
__global__ __launch_bounds__(256) void aggregate64_kernel(
        const __half* __restrict__ hs, const int* __restrict__ row_off,
        const int* __restrict__ deg, const int* __restrict__ ssrc,
        const float* __restrict__ dinv, const float* __restrict__ bias,
        float* __restrict__ out) {
    int node = (blockIdx.x * 256 + threadIdx.x) >> 6;
    int lane = threadIdx.x & 63;
    if (node >= N_NODES) return;
    int beg = row_off[node];
    int d   = deg[node];
    float di = dinv[node];
    int qt = lane >> 4, sl = lane & 15;
    const float2* Hq = (const float2*)hs;        // [N+1][16] 8B chunks
    float4 acc = make_float4(0.f, 0.f, 0.f, 0.f);
    for (int j = 0; j < d; j += 32) {            // padded span covers ceil32(d)
        int s[8]; float2 v[8];
#pragma unroll
        for (int u = 0; u < 8; u++) s[u] = ssrc[beg + j + 4 * u + qt];
#pragma unroll
        for (int u = 0; u < 8; u++) v[u] = Hq[(size_t)s[u] * 16 + sl];
#pragma unroll
        for (int u = 0; u < 8; u++) {
            float2 f0 = __half22float2(((const __half2*)&v[u])[0]);
            float2 f1 = __half22float2(((const __half2*)&v[u])[1]);
            acc.x += f0.x; acc.y += f0.y; acc.z += f1.x; acc.w += f1.y;
        }
    }
    acc.x += __shfl_xor(acc.x, 16, 64);
    acc.y += __shfl_xor(acc.y, 16, 64);
    acc.z += __shfl_xor(acc.z, 16, 64);
    acc.w += __shfl_xor(acc.w, 16, 64);
    acc.x += __shfl_xor(acc.x, 32, 64);
    acc.y += __shfl_xor(acc.y, 32, 64);
    acc.z += __shfl_xor(acc.z, 32, 64);
    acc.w += __shfl_xor(acc.w, 32, 64);
    if (lane < 16) {
        float2 sv = Hq[(size_t)node * 16 + sl];  // self-loop
        float2 f0 = __half22float2(((const __half2*)&sv)[0]);
        float2 f1 = __half22float2(((const __half2*)&sv)[1]);
        float4 b = ((const float4*)bias)[sl];
        float4 o;
        o.x = fmaf(di, acc.x + f0.x, b.x);
        o.y = fmaf(di, acc.y + f0.y, b.y);
        o.z = fmaf(di, acc.z + f1.x, b.z);
        o.w = fmaf(di, acc.w + f1.y, b.w);
        ((float4*)out)[(size_t)node * 16 + sl] = o;
    }
}

// ---------------- launch ----------------

extern "C" void kernel_launch(void* const* d_in, const int* in_sizes, int n_in,
                              void* d_out, int out_size, void* d_ws, size_t ws_size,
                              hipStream_t stream) {
    const float* x  = (const float*)d_in[0];   // [N,128]
    const int*   ei = (const int*)d_in[1];     // [2,E]
    const float* W1 = (const float*)d_in[2];   // [128,128]
    const float* b1 = (const float*)d_in[3];   // [128]
    const float* W2 = (const float*)d_in[4];   // [128,64]
    const float* b2 = (const float*)d_in[5];   // [64]
    float* out = (float*)d_out;                // [N,64]

    const int* src = ei;
    const int* dst = ei + N_EDGES;

    char* p = (char*)d_ws;
    size_t off = 0;
    auto alloc = [&](size_t bytes) { void* q = p + off; off += (bytes + 255) & ~(size_t)255; return q; };
    float*    dinv    = (float*)   alloc(N_NODES * 4);
    int*      deg     = (int*)     alloc(N_NODES * 4);
    int*      row_off = (int*)     alloc(N_NODES * 4);
    int*      gcur    = (int*)     alloc(NBIN * 4);
    int*      ssrc    = (int*)     alloc((size_t)NBIN * CAP2 * 4);  // 10.4 MB
    unsigned* ebin    = (unsigned*)alloc((size_t)NBIN * CAP * 4);   // 4.0 MB
    __bf16*   w1hi    = (__bf16*)  alloc(128 * 128 * 2);
    __bf16*   w1lo    = (__bf16*)  alloc(128 * 128 * 2);
    __bf16*   w2hi    = (__bf16*)  alloc(128 * 64 * 2);
    __bf16*   w2lo    = (__bf16*)  alloc(128 * 64 * 2);
    __half*   hs1     = (__half*)  alloc((size_t)(N_NODES + 1) * 128 * 2);
    __half*   hs2     = (__half*)  alloc((size_t)(N_NODES + 1) * 64 * 2);
    float*    x2      = (float*)   alloc((size_t)N_NODES * 128 * 4);

    // 7 launches total
    prep_kernel<<<13, 256, 0, stream>>>(W1, W2, w1hi, w1lo, w2hi, w2lo, gcur, hs1, hs2);
    bin_scatter_kernel<<<NB_SCAT, 256, 0, stream>>>(src, dst, gcur, ebin);
    bin_build_kernel<<<NBIN, 256, 0, stream>>>(ebin, gcur, deg, row_off, dinv, ssrc);

    gemm_mfma_kernel<128><<<(N_NODES + 63) / 64, 256, 0, stream>>>(x, w1hi, w1lo, dinv, hs1);
    aggregate128_kernel<true><<<(N_NODES * 64 + 255) / 256, 256, 0, stream>>>(
        hs1, row_off, deg, ssrc, dinv, b1, x2);

    gemm_mfma_kernel<64><<<(N_NODES + 63) / 64, 256, 0, stream>>>(x2, w2hi, w2lo, dinv, hs2);
    aggregate64_kernel<<<(N_NODES * 64 + 255) / 256, 256, 0, stream>>>(
        hs2, row_off, deg, ssrc, dinv, b2, out);
}

// Round 12
// 184.771 us; speedup vs baseline: 1.4895x; 1.0009x over previous
//
#include <hip/hip_runtime.h>
#include <hip/hip_fp16.h>

// GCN 2-layer: N=50000 nodes, E=800000 edges, 128 -> 128(relu) -> 64
// R12: (a) bin_scatter B_CHUNK 4096->2048 (196->391 blocks: full CU coverage)
//      (b) gemm64 FUSED into agg128: block=1024thr=16 waves=16 nodes; x2 rows
//          parked in LDS (f32, padded 132), one barrier, waves 0-3 do the
//          16x64 split-bf16 MFMA tile from LDS -> hs2. Kills the 51MB x2
//          round-trip + one launch. x2 precision unchanged (f32 via LDS).
// Evidence log: R2 MLP depth win; R4/R9 sliced layouts dead (instr cost /
// 128B-line thrash); flat gather 86.6MB compulsory; R11 sentinel pad win;
// top-5 now 100% harness poison fills (~50us fixed, untouchable).

#define N_NODES 50000
#define N_EDGES 800000
#define BINW    128
#define NBIN    391                    // ceil(50000/128)
#define CAP     2560                   // mean bin load 2046, ~11 sigma margin
#define CAP2    6656                   // padded: up to 2560 + 128*31
#define B_CHUNK 2048
#define NB_SCAT ((N_EDGES + B_CHUNK - 1) / B_CHUNK)   // 391

typedef __bf16 bf16x8 __attribute__((ext_vector_type(8)));
typedef float  f32x4  __attribute__((ext_vector_type(4)));

// ---------------- prep: W-frags, zero gcur, zero sentinel rows ----------------
template<int N>
__device__ inline void wprep_body(const float* __restrict__ W,
                                  __bf16* __restrict__ hi, __bf16* __restrict__ lo,
                                  int idx) {
    if (idx >= (N / 16) * 4 * 64) return;
    int l = idx & 63;
    int s = (idx >> 6) & 3;
    int c = idx >> 8;
    int n = c * 16 + (l & 15);
    int k0 = s * 32 + (l >> 4) * 8;
#pragma unroll
    for (int j = 0; j < 8; j++) {
        float w = W[(k0 + j) * N + n];
        __bf16 h = (__bf16)w;
        hi[idx * 8 + j] = h;
        lo[idx * 8 + j] = (__bf16)(w - (float)h);
    }
}

__global__ __launch_bounds__(256) void prep_kernel(
        const float* __restrict__ W1, const float* __restrict__ W2,
        __bf16* __restrict__ w1hi, __bf16* __restrict__ w1lo,
        __bf16* __restrict__ w2hi, __bf16* __restrict__ w2lo,
        int* __restrict__ gcur, __half* __restrict__ hs1, __half* __restrict__ hs2) {
    int b = blockIdx.x, tid = threadIdx.x;
    if (b < 8)       wprep_body<128>(W1, w1hi, w1lo, b * 256 + tid);
    else if (b < 12) wprep_body<64> (W2, w2hi, w2lo, (b - 8) * 256 + tid);
    else {
        for (int i = tid; i < NBIN; i += 256) gcur[i] = 0;
        if (tid < 128) hs1[(size_t)N_NODES * 128 + tid] = __float2half(0.f);
        if (tid < 64)  hs2[(size_t)N_NODES * 64 + tid] = __float2half(0.f);
    }
}

// ---------------- bin_scatter: one edge pass -> per-bin packed (dst<<16|src) -------

__global__ __launch_bounds__(256) void bin_scatter_kernel(
        const int* __restrict__ src, const int* __restrict__ dst,
        int* __restrict__ gcur, unsigned* __restrict__ ebin) {
    __shared__ int cnt[512];
    __shared__ int boff[512];
    __shared__ int bcur[512];
    __shared__ int gbase[512];
    __shared__ unsigned stage[B_CHUNK];
    __shared__ int ex[256];
    int tid = threadIdx.x;
    int e0 = blockIdx.x * B_CHUNK;

    cnt[tid] = 0; cnt[tid + 256] = 0;
    __syncthreads();

    unsigned key[8]; int bins[8];
#pragma unroll
    for (int i = 0; i < 8; i++) {
        int e = e0 + tid + i * 256;               // coalesced
        if (e < N_EDGES) {
            int d = dst[e], s = src[e];
            key[i]  = ((unsigned)d << 16) | (unsigned)s;
            bins[i] = d >> 7;
            atomicAdd(&cnt[bins[i]], 1);
        } else bins[i] = -1;
    }
    __syncthreads();

    // exclusive scan of 512 bin counts with 256 threads (2 bins each)
    int a = cnt[2 * tid], b = cnt[2 * tid + 1];
    ex[tid] = a + b;
    __syncthreads();
    for (int off = 1; off < 256; off <<= 1) {
        int t = (tid >= off) ? ex[tid - off] : 0;
        __syncthreads();
        ex[tid] += t;
        __syncthreads();
    }
    int myex = ex[tid] - (a + b);
    boff[2 * tid] = myex;     boff[2 * tid + 1] = myex + a;
    bcur[2 * tid] = myex;     bcur[2 * tid + 1] = myex + a;
    __syncthreads();

    // compact into bin-contiguous staging
#pragma unroll
    for (int i = 0; i < 8; i++) {
        if (bins[i] >= 0) {
            int p = atomicAdd(&bcur[bins[i]], 1);
            stage[p] = key[i];
        }
    }

    // bulk-reserve global bin space (one atomic per non-empty (block,bin))
    __syncthreads();
    for (int b2 = tid; b2 < NBIN; b2 += 256) {
        int c = cnt[b2];
        gbase[b2] = (c > 0) ? atomicAdd(&gcur[b2], c) : 0;
    }
    __syncthreads();

    int total = N_EDGES - e0; if (total > B_CHUNK) total = B_CHUNK;
    for (int i = tid; i < total; i += 256) {
        unsigned k = stage[i];
        int bin = (int)(k >> 23);                 // dst>>7
        int idx = gbase[bin] + (i - boff[bin]);
        if (idx < CAP) ebin[(size_t)bin * CAP + idx] = k;  // guard (11-sigma)
    }
}

// ---------------- bin_build: histogram + padded scan + sentinel fill ---------------
__global__ __launch_bounds__(256) void bin_build_kernel(
        const unsigned* __restrict__ ebin, const int* __restrict__ gcur,
        int* __restrict__ deg, int* __restrict__ row_off,
        float* __restrict__ dinv, int* __restrict__ ssrc) {
    __shared__ int dl[BINW];
    __shared__ int pref[BINW];
    __shared__ int cur[BINW];
    __shared__ int padTotal;
    int bin = blockIdx.x, tid = threadIdx.x;
    if (tid < BINW) dl[tid] = 0;
    __syncthreads();
    int cnt = gcur[bin]; if (cnt > CAP) cnt = CAP;
    const unsigned* eb = ebin + (size_t)bin * CAP;
    for (int i = tid; i < cnt; i += 256)
        atomicAdd(&dl[(eb[i] >> 16) & 127], 1);
    __syncthreads();
    // Hillis-Steele inclusive scan over 128 PADDED counts
    int pc = 0;
    if (tid < BINW) { pc = (dl[tid] + 31) & ~31; pref[tid] = pc; }
    __syncthreads();
    for (int off = 1; off < BINW; off <<= 1) {
        int t = 0;
        if (tid < BINW && tid >= off) t = pref[tid - off];
        __syncthreads();
        if (tid < BINW) pref[tid] += t;
        __syncthreads();
    }
    if (tid < BINW) {
        int ex = pref[tid] - pc;                  // padded exclusive prefix
        cur[tid] = ex;
        int node = bin * BINW + tid;
        if (node < N_NODES) {
            deg[node]     = dl[tid];
            row_off[node] = bin * CAP2 + ex;
            dinv[node]    = rsqrtf((float)(dl[tid] + 1));   // +1 self-loop
        }
        if (tid == BINW - 1) padTotal = pref[tid];
    }
    __syncthreads();
    int pt = padTotal;
    int* sb = ssrc + (size_t)bin * CAP2;
    for (int i = tid; i < pt; i += 256) sb[i] = N_NODES;    // sentinel prefill
    __syncthreads();
    for (int i = tid; i < cnt; i += 256) {
        unsigned k = eb[i];
        int p = atomicAdd(&cur[(k >> 16) & 127], 1);
        sb[p] = (int)(k & 0xFFFFu);
    }
}

// ---------------- GEMM layer1: hs1[row][128] = fp16( dinv[row]*(X@W1)[row] ) ------
__global__ __launch_bounds__(256) void gemm_mfma128_kernel(
        const float* __restrict__ X, const __bf16* __restrict__ Whi,
        const __bf16* __restrict__ Wlo, const float* __restrict__ dinv,
        __half* __restrict__ hs) {
    constexpr int NC = 8;
    int tid = threadIdx.x;
    int w = tid >> 6, lane = tid & 63;
    int q = lane >> 4, lr = lane & 15;
    int rb = blockIdx.x * 64 + w * 16;
    int row = rb + lr;
    int rowc = (row < N_NODES) ? row : (N_NODES - 1);

    f32x4 acc[NC];
#pragma unroll
    for (int c = 0; c < NC; c++) acc[c] = (f32x4){0.f, 0.f, 0.f, 0.f};

#pragma unroll
    for (int s = 0; s < 4; s++) {
        const float* xp = X + (size_t)rowc * 128 + s * 32 + q * 8;
        float4 x0 = *(const float4*)xp;
        float4 x1 = *(const float4*)(xp + 4);
        float xv[8] = {x0.x, x0.y, x0.z, x0.w, x1.x, x1.y, x1.z, x1.w};
        bf16x8 a_hi, a_lo;
#pragma unroll
        for (int j = 0; j < 8; j++) {
            __bf16 h = (__bf16)xv[j];
            a_hi[j] = h;
            a_lo[j] = (__bf16)(xv[j] - (float)h);
        }
#pragma unroll
        for (int c = 0; c < NC; c++) {
            size_t fo = (size_t)((c * 4 + s) * 64 + lane) * 8;
            bf16x8 bh = *(const bf16x8*)(Whi + fo);
            bf16x8 bl = *(const bf16x8*)(Wlo + fo);
            acc[c] = __builtin_amdgcn_mfma_f32_16x16x32_bf16(a_hi, bh, acc[c], 0, 0, 0);
            acc[c] = __builtin_amdgcn_mfma_f32_16x16x32_bf16(a_lo, bh, acc[c], 0, 0, 0);
            acc[c] = __builtin_amdgcn_mfma_f32_16x16x32_bf16(a_hi, bl, acc[c], 0, 0, 0);
        }
    }

    // C/D layout: col = c*16 + lr, row(within 16) = q*4 + r
#pragma unroll
    for (int r = 0; r < 4; r++) {
        int grow = rb + q * 4 + r;
        if (grow < N_NODES) {
            float sc = dinv[grow];
#pragma unroll
            for (int c = 0; c < NC; c++) {
                hs[(size_t)grow * 128 + c * 16 + lr] = __float2half(acc[c][r] * sc);
            }
        }
    }
}

// ---------------- FUSED: agg128(+relu) -> LDS x2 rows -> 16x64 MFMA -> hs2 --------
// block = 1024 thr = 16 waves = 16 nodes (50000 = 3125*16 exact).
// Gather phase identical to R11 agg128 (sentinel lists, 8 gathers in flight).
// x2 rows stay f32 in LDS (no precision change). Waves 0-3 then compute
// hs2[rb..rb+16][c*16..] = fp16(dinv*(x2@W2)) via split-bf16 MFMA.
__global__ __launch_bounds__(1024) void fused_agg_gemm_kernel(
        const __half* __restrict__ hs1, const int* __restrict__ row_off,
        const int* __restrict__ deg, const int* __restrict__ ssrc,
        const float* __restrict__ dinv, const float* __restrict__ bias,
        const __bf16* __restrict__ w2hi, const __bf16* __restrict__ w2lo,
        __half* __restrict__ hs2) {
    __shared__ float x2buf[16][132];              // pad 132: 2-way banks (free)
    int wave = threadIdx.x >> 6;
    int lane = threadIdx.x & 63;
    int rb = blockIdx.x * 16;
    int node = rb + wave;                         // always < N_NODES

    int beg = row_off[node];
    int d   = deg[node];
    float di = dinv[node];
    int hf = lane >> 5, sl = lane & 31;
    const float2* Hq = (const float2*)hs1;        // [N+1][32] 8B chunks
    float4 acc = make_float4(0.f, 0.f, 0.f, 0.f);
    for (int j = 0; j < d; j += 16) {             // padded span, sentinel-safe
        int s[8]; float2 v[8];
#pragma unroll
        for (int u = 0; u < 8; u++) s[u] = ssrc[beg + j + 2 * u + hf];
#pragma unroll
        for (int u = 0; u < 8; u++) v[u] = Hq[(size_t)s[u] * 32 + sl];
#pragma unroll
        for (int u = 0; u < 8; u++) {
            float2 f0 = __half22float2(((const __half2*)&v[u])[0]);
            float2 f1 = __half22float2(((const __half2*)&v[u])[1]);
            acc.x += f0.x; acc.y += f0.y; acc.z += f1.x; acc.w += f1.y;
        }
    }
    acc.x += __shfl_xor(acc.x, 32, 64);
    acc.y += __shfl_xor(acc.y, 32, 64);
    acc.z += __shfl_xor(acc.z, 32, 64);
    acc.w += __shfl_xor(acc.w, 32, 64);
    if (hf == 0) {
        float2 sv = Hq[(size_t)node * 32 + sl];   // self-loop
        float2 f0 = __half22float2(((const __half2*)&sv)[0]);
        float2 f1 = __half22float2(((const __half2*)&sv)[1]);
        float4 b = ((const float4*)bias)[sl];
        float4 o;
        o.x = fmaxf(fmaf(di, acc.x + f0.x, b.x), 0.f);     // relu
        o.y = fmaxf(fmaf(di, acc.y + f0.y, b.y), 0.f);
        o.z = fmaxf(fmaf(di, acc.z + f1.x, b.z), 0.f);
        o.w = fmaxf(fmaf(di, acc.w + f1.y, b.w), 0.f);
        *(float4*)&x2buf[wave][4 * sl] = o;
    }
    __syncthreads();

    // GEMM phase: waves 0-3, wave = col-frag c (16 cols each)
    if (threadIdx.x < 256) {
        int c = wave;
        int q = lane >> 4, lr = lane & 15;
        f32x4 g = (f32x4){0.f, 0.f, 0.f, 0.f};
#pragma unroll
        for (int s = 0; s < 4; s++) {
            const float* xp = &x2buf[lr][s * 32 + q * 8];
            float4 a0 = *(const float4*)xp;
            float4 a1 = *(const float4*)(xp + 4);
            float xv[8] = {a0.x, a0.y, a0.z, a0.w, a1.x, a1.y, a1.z, a1.w};
            bf16x8 a_hi, a_lo;
#pragma unroll
            for (int j = 0; j < 8; j++) {
                __bf16 h = (__bf16)xv[j];
                a_hi[j] = h;
                a_lo[j] = (__bf16)(xv[j] - (float)h);
            }
            size_t fo = (size_t)((c * 4 + s) * 64 + lane) * 8;
            bf16x8 bh = *(const bf16x8*)(w2hi + fo);
            bf16x8 bl = *(const bf16x8*)(w2lo + fo);
            g = __builtin_amdgcn_mfma_f32_16x16x32_bf16(a_hi, bh, g, 0, 0, 0);
            g = __builtin_amdgcn_mfma_f32_16x16x32_bf16(a_lo, bh, g, 0, 0, 0);
            g = __builtin_amdgcn_mfma_f32_16x16x32_bf16(a_hi, bl, g, 0, 0, 0);
        }
#pragma unroll
        for (int r = 0; r < 4; r++) {
            int grow = rb + q * 4 + r;
            hs2[(size_t)grow * 64 + c * 16 + lr] = __float2half(g[r] * dinv[grow]);
        }
    }
}

// ---------------- Aggregate CH=64: wave/node, 8B/lane = 4 rows/instr --------------
__global__ __launch_bounds__(256) void aggregate64_kernel(
        const __half* __restrict__ hs, const int* __restrict__ row_off,
        const int* __restrict__ deg, const int* __restrict__ ssrc,
        const float* __restrict__ dinv, const float* __restrict__ bias,
        float* __restrict__ out) {
    int node = (blockIdx.x * 256 + threadIdx.x) >> 6;
    int lane = threadIdx.x & 63;
    if (node >= N_NODES) return;
    int beg = row_off[node];
    int d   = deg[node];
    float di = dinv[node];
    int qt = lane >> 4, sl = lane & 15;
    const float2* Hq = (const float2*)hs;        // [N+1][16] 8B chunks
    float4 acc = make_float4(0.f, 0.f, 0.f, 0.f);
    for (int j = 0; j < d; j += 32) {            // padded span, sentinel-safe
        int s[8]; float2 v[8];
#pragma unroll
        for (int u = 0; u < 8; u++) s[u] = ssrc[beg + j + 4 * u + qt];
#pragma unroll
        for (int u = 0; u < 8; u++) v[u] = Hq[(size_t)s[u] * 16 + sl];
#pragma unroll
        for (int u = 0; u < 8; u++) {
            float2 f0 = __half22float2(((const __half2*)&v[u])[0]);
            float2 f1 = __half22float2(((const __half2*)&v[u])[1]);
            acc.x += f0.x; acc.y += f0.y; acc.z += f1.x; acc.w += f1.y;
        }
    }
    acc.x += __shfl_xor(acc.x, 16, 64);
    acc.y += __shfl_xor(acc.y, 16, 64);
    acc.z += __shfl_xor(acc.z, 16, 64);
    acc.w += __shfl_xor(acc.w, 16, 64);
    acc.x += __shfl_xor(acc.x, 32, 64);
    acc.y += __shfl_xor(acc.y, 32, 64);
    acc.z += __shfl_xor(acc.z, 32, 64);
    acc.w += __shfl_xor(acc.w, 32, 64);
    if (lane < 16) {
        float2 sv = Hq[(size_t)node * 16 + sl];  // self-loop
        float2 f0 = __half22float2(((const __half2*)&sv)[0]);
        float2 f1 = __half22float2(((const __half2*)&sv)[1]);
        float4 b = ((const float4*)bias)[sl];
        float4 o;
        o.x = fmaf(di, acc.x + f0.x, b.x);
        o.y = fmaf(di, acc.y + f0.y, b.y);
        o.z = fmaf(di, acc.z + f1.x, b.z);
        o.w = fmaf(di, acc.w + f1.y, b.w);
        ((float4*)out)[(size_t)node * 16 + sl] = o;
    }
}

// ---------------- launch ----------------

extern "C" void kernel_launch(void* const* d_in, const int* in_sizes, int n_in,
                              void* d_out, int out_size, void* d_ws, size_t ws_size,
                              hipStream_t stream) {
    const float* x  = (const float*)d_in[0];   // [N,128]
    const int*   ei = (const int*)d_in[1];     // [2,E]
    const float* W1 = (const float*)d_in[2];   // [128,128]
    const float* b1 = (const float*)d_in[3];   // [128]
    const float* W2 = (const float*)d_in[4];   // [128,64]
    const float* b2 = (const float*)d_in[5];   // [64]
    float* out = (float*)d_out;                // [N,64]

    const int* src = ei;
    const int* dst = ei + N_EDGES;

    char* p = (char*)d_ws;
    size_t off = 0;
    auto alloc = [&](size_t bytes) { void* q = p + off; off += (bytes + 255) & ~(size_t)255; return q; };
    float*    dinv    = (float*)   alloc(N_NODES * 4);
    int*      deg     = (int*)     alloc(N_NODES * 4);
    int*      row_off = (int*)     alloc(N_NODES * 4);
    int*      gcur    = (int*)     alloc(NBIN * 4);
    int*      ssrc    = (int*)     alloc((size_t)NBIN * CAP2 * 4);  // 10.4 MB
    unsigned* ebin    = (unsigned*)alloc((size_t)NBIN * CAP * 4);   // 4.0 MB
    __bf16*   w1hi    = (__bf16*)  alloc(128 * 128 * 2);
    __bf16*   w1lo    = (__bf16*)  alloc(128 * 128 * 2);
    __bf16*   w2hi    = (__bf16*)  alloc(128 * 64 * 2);
    __bf16*   w2lo    = (__bf16*)  alloc(128 * 64 * 2);
    __half*   hs1     = (__half*)  alloc((size_t)(N_NODES + 1) * 128 * 2);
    __half*   hs2     = (__half*)  alloc((size_t)(N_NODES + 1) * 64 * 2);

    // 6 launches total
    prep_kernel<<<13, 256, 0, stream>>>(W1, W2, w1hi, w1lo, w2hi, w2lo, gcur, hs1, hs2);
    bin_scatter_kernel<<<NB_SCAT, 256, 0, stream>>>(src, dst, gcur, ebin);
    bin_build_kernel<<<NBIN, 256, 0, stream>>>(ebin, gcur, deg, row_off, dinv, ssrc);

    gemm_mfma128_kernel<<<(N_NODES + 63) / 64, 256, 0, stream>>>(x, w1hi, w1lo, dinv, hs1);
    fused_agg_gemm_kernel<<<N_NODES / 16, 1024, 0, stream>>>(
        hs1, row_off, deg, ssrc, dinv, b1, w2hi, w2lo, hs2);
    aggregate64_kernel<<<(N_NODES * 64 + 255) / 256, 256, 0, stream>>>(
        hs2, row_off, deg, ssrc, dinv, b2, out);
}